// Round 19
// baseline (739.697 us; speedup 1.0000x reference)
//
#include <hip/hip_runtime.h>
#include <hip/hip_bf16.h>
#include <math.h>

#define B_ 4
#define N_ 2048
#define D_ 1024
#define WIN_ 4
#define KTOP 8
#define ALPHA_ 0.3f
#define SCALE_ (1.0f/32.0f)
#define NCH 16          // N_/128 col chunks
#define INV2048 0.00048828125f

typedef unsigned short ushortT;
typedef _Float16 halfT;
typedef __attribute__((ext_vector_type(8))) _Float16 half8v;  // 8 fp16 (4 VGPR)
typedef __attribute__((ext_vector_type(4))) float f32x4;

__device__ inline ushortT h2u(halfT h){ union{halfT h; ushortT u;} x; x.h=h; return x.u; }
__device__ inline halfT  u2h(ushortT u){ union{halfT h; ushortT u;} x; x.u=u; return x.h; }
__device__ inline float  uh2f(ushortT u){ return (float)u2h(u); }

// async global->LDS, 16B per lane (dest = wave-uniform base + lane*16)
__device__ __forceinline__ void gll16(const ushortT* g, ushortT* l) {
    __builtin_amdgcn_global_load_lds(
        (const __attribute__((address_space(1))) void*)g,
        (__attribute__((address_space(3))) void*)l, 16, 0, 0);
}

// ---------------------------------------------------------------------------
// prep_all: ONE launch for all input prep.
//   blocks [0, 8192):      mu f32 -> 2 fp16 planes (a, scaled residual B)
//   blocks [8192, 16384):  weight transposes (7 tasks, 32x32 tiles)
// ---------------------------------------------------------------------------
__global__ __launch_bounds__(256)
void prep_all(const float* __restrict__ mu, const float* __restrict__ Wm1,
              const float* __restrict__ Wm2, const float* __restrict__ Wv,
              const float* __restrict__ Wo, const float* __restrict__ Wq,
              const float* __restrict__ Wk,
              ushortT* __restrict__ mu_a, ushortT* __restrict__ mu_B,
              ushortT* __restrict__ WtF, ushortT* __restrict__ Wt_m2,
              ushortT* __restrict__ Wt_v, ushortT* __restrict__ Wt_o,
              ushortT* __restrict__ WqT_a, ushortT* __restrict__ WqT_B,
              ushortT* __restrict__ WkT_a, ushortT* __restrict__ WkT_B)
{
    const int bid = blockIdx.x;
    if (bid < 8192) {                       // ---- split2_mu ----
        size_t base = ((size_t)bid * 256 + threadIdx.x) * 4;
        float4 v = *reinterpret_cast<const float4*>(&mu[base]);
        float vv[4] = {v.x, v.y, v.z, v.w};
        ushort4 pa, pb;
#pragma unroll
        for (int j = 0; j < 4; ++j) {
            float f = vv[j];
            halfT a = (halfT)f;  float r = f - (float)a;
            halfT b = (halfT)(r * 2048.0f);
            ((ushortT*)&pa)[j] = h2u(a); ((ushortT*)&pb)[j] = h2u(b);
        }
        *reinterpret_cast<ushort4*>(&mu_a[base]) = pa;
        *reinterpret_cast<ushort4*>(&mu_B[base]) = pb;
        return;
    }
    // ---- transposes ----
    __shared__ float t[32][33];
    int b = bid - 8192;
    const float* W; ushortT* Pa; ushortT* Pb = nullptr;
    int K, lb, split = 0;
    if (b < 1024)      { W = Wm1;                       Pa = WtF;                     K = 1024; lb = b; }
    else if (b < 2048) { W = Wm1 + (size_t)1024 * 1024; Pa = WtF + (size_t)1024*1024; K = 1024; lb = b - 1024; }
    else if (b < 3072) { W = Wm2;  Pa = Wt_m2; K = 1024; lb = b - 2048; }
    else if (b < 4096) { W = Wv;   Pa = Wt_v;  K = 1024; lb = b - 3072; }
    else if (b < 6144) { W = Wo;   Pa = Wt_o;  K = 2048; lb = b - 4096; }
    else if (b < 7168) { W = Wq;   Pa = WqT_a; Pb = WqT_B; K = 1024; lb = b - 6144; split = 1; }
    else               { W = Wk;   Pa = WkT_a; Pb = WkT_B; K = 1024; lb = b - 7168; split = 1; }
    const int Nn = 1024;
    const int k0 = (K == 2048) ? (lb & 63) * 32 : (lb & 31) * 32;
    const int n0 = (K == 2048) ? (lb >> 6) * 32 : (lb >> 5) * 32;
    const int tx = threadIdx.x & 31, ty8 = threadIdx.x >> 5;
#pragma unroll
    for (int p = 0; p < 4; ++p) {
        int kk = p * 8 + ty8;
        t[kk][tx] = W[(size_t)(k0 + kk) * Nn + n0 + tx];
    }
    __syncthreads();
#pragma unroll
    for (int p = 0; p < 4; ++p) {
        int nn = p * 8 + ty8;
        float f = t[tx][nn];
        size_t o = (size_t)(n0 + nn) * K + k0 + tx;
        if (split) {
            halfT a = (halfT)f;  float r = f - (float)a;
            halfT bb = (halfT)(r * 2048.0f);
            Pa[o] = h2u(a); Pb[o] = h2u(bb);
        } else {
            Pa[o] = h2u((halfT)f);
        }
    }
}

// ---------------------------------------------------------------------------
// fp16 MFMA GEMM core body (proven): 128x128 tile, BK=64, 4 waves, 64x64/wave.
// ---------------------------------------------------------------------------
__device__ __forceinline__ void gemm_core_h(
    const ushortT* __restrict__ A, int lda, const ushortT* __restrict__ Bt, int ldb,
    const float* __restrict__ bias, void* __restrict__ Cout, int ldc, int K,
    int m0, int n0, int outHalf, ushortT* AsL, ushortT* BsL)
{
    const int tid = threadIdx.x;
    const int w = tid >> 6, lane = tid & 63;
    const int wr = w >> 1, wc = w & 1;

    f32x4 acc[4][4];
#pragma unroll
    for (int mi = 0; mi < 4; ++mi)
#pragma unroll
        for (int ni = 0; ni < 4; ++ni) acc[mi][ni] = (f32x4){0.f, 0.f, 0.f, 0.f};

    for (int k0 = 0; k0 < K; k0 += 64) {
#pragma unroll
        for (int it = 0; it < 4; ++it) {
            int idx = tid + it * 256;        // 0..1023
            int row = idx >> 3, c = idx & 7;
            int4 va = *reinterpret_cast<const int4*>(&A[(size_t)(m0 + row) * lda + k0 + c * 8]);
            *reinterpret_cast<int4*>(&AsL[row * 72 + c * 8]) = va;
            int4 vb = *reinterpret_cast<const int4*>(&Bt[(size_t)(n0 + row) * ldb + k0 + c * 8]);
            *reinterpret_cast<int4*>(&BsL[row * 72 + c * 8]) = vb;
        }
        __syncthreads();
#pragma unroll
        for (int kh = 0; kh < 2; ++kh) {
            const int ko = kh * 32 + (lane >> 4) * 8;
            const int rr = lane & 15;
            half8v af[4], bf[4];
#pragma unroll
            for (int mi = 0; mi < 4; ++mi)
                af[mi] = *reinterpret_cast<const half8v*>(&AsL[(wr * 64 + mi * 16 + rr) * 72 + ko]);
#pragma unroll
            for (int ni = 0; ni < 4; ++ni)
                bf[ni] = *reinterpret_cast<const half8v*>(&BsL[(wc * 64 + ni * 16 + rr) * 72 + ko]);
#pragma unroll
            for (int mi = 0; mi < 4; ++mi)
#pragma unroll
                for (int ni = 0; ni < 4; ++ni)
                    acc[mi][ni] = __builtin_amdgcn_mfma_f32_16x16x32_f16(
                        af[mi], bf[ni], acc[mi][ni], 0, 0, 0);
        }
        __syncthreads();
    }

    const int r4 = (lane >> 4) * 4, cl = lane & 15;
#pragma unroll
    for (int mi = 0; mi < 4; ++mi)
#pragma unroll
        for (int ni = 0; ni < 4; ++ni) {
            int row = m0 + wr * 64 + mi * 16 + r4;
            int col = n0 + wc * 64 + ni * 16 + cl;
            float bb = bias ? bias[col] : 0.f;
#pragma unroll
            for (int r = 0; r < 4; ++r) {
                float v = acc[mi][ni][r] + bb;
                if (outHalf)
                    ((ushortT*)Cout)[(size_t)(row + r) * ldc + col] = h2u((halfT)v);
                else
                    ((float*)Cout)[(size_t)(row + r) * ldc + col] = v;
            }
        }
}

template<int OUT_HALF>
__global__ __launch_bounds__(256)
void mfma_gemm_h(const ushortT* __restrict__ A, int lda,
                 const ushortT* __restrict__ Bt, int ldb,
                 const float* __restrict__ bias,
                 void* __restrict__ Cout, int ldc, int K)
{
    __shared__ ushortT AsL[128 * 72];
    __shared__ ushortT BsL[128 * 72];
    gemm_core_h(A, lda, Bt, ldb, bias, Cout, ldc, K,
                blockIdx.y * 128, blockIdx.x * 128, OUT_HALF, AsL, BsL);
}

// merged: blocks [0,1024) = PF pre-act gemm (Nc=2048, f32 out);
//         blocks [1024,1536) = V gemm (fp16 out)
__global__ __launch_bounds__(256)
void gemm_pf_v(const ushortT* __restrict__ mu_a,
               const ushortT* __restrict__ WtF, const ushortT* __restrict__ Wt_v,
               const float* __restrict__ bv,
               float* __restrict__ PF, ushortT* __restrict__ Vb16)
{
    __shared__ ushortT AsL[128 * 72];
    __shared__ ushortT BsL[128 * 72];
    const int bid = blockIdx.x;
    if (bid < 1024) {
        gemm_core_h(mu_a, D_, WtF, D_, (const float*)nullptr, (void*)PF, 2 * D_, D_,
                    (bid >> 4) * 128, (bid & 15) * 128, 0, AsL, BsL);
    } else {
        const int b2 = bid - 1024;
        gemm_core_h(mu_a, D_, Wt_v, D_, bv, (void*)Vb16, D_, D_,
                    (b2 >> 3) * 128, (b2 & 7) * 128, 1, AsL, BsL);
    }
}

// ---------------------------------------------------------------------------
// Fused pre-act: P is [8192][2048] f32 (cols 0..1023 = self pre-act no bias,
// cols 1024..2047 = neighbor pre-act). S = mean_w silu(P_self + bm1 +
// P_neigh[n-w]), output fp16.
// ---------------------------------------------------------------------------
__global__ __launch_bounds__(256)
void silu_mean(const float* __restrict__ P, const float* __restrict__ bm1,
               ushortT* __restrict__ Sb)
{
    size_t idx4 = (size_t)blockIdx.x * blockDim.x + threadIdx.x;
    size_t base = idx4 << 2;                 // logical [row][1024]
    int row = (int)(base >> 10);
    int col = (int)(base & 1023);
    int n = row & (N_ - 1);
    float4 a = *reinterpret_cast<const float4*>(&P[(size_t)row * 2048 + col]);
    float4 bb = *reinterpret_cast<const float4*>(&bm1[col]);
    a.x += bb.x; a.y += bb.y; a.z += bb.z; a.w += bb.w;
    float sx = 0.f, sy = 0.f, sz = 0.f, sw = 0.f;
#pragma unroll
    for (int w = 1; w <= WIN_; ++w) {
        float xx = a.x, xy = a.y, xz = a.z, xw = a.w;
        if (n >= w) {
            const float4 nb = *reinterpret_cast<const float4*>(
                &P[(size_t)(row - w) * 2048 + 1024 + col]);
            xx += nb.x; xy += nb.y; xz += nb.z; xw += nb.w;
        }
        sx += xx / (1.f + __expf(-xx));
        sy += xy / (1.f + __expf(-xy));
        sz += xz / (1.f + __expf(-xz));
        sw += xw / (1.f + __expf(-xw));
    }
    ushort4 o = {h2u((halfT)(sx * 0.25f)), h2u((halfT)(sy * 0.25f)),
                 h2u((halfT)(sz * 0.25f)), h2u((halfT)(sw * 0.25f))};
    *reinterpret_cast<ushort4*>(&Sb[base]) = o;
}

// ---------------------------------------------------------------------------
__device__ inline void topk_insert(float (&tv)[KTOP], int (&ti)[KTOP], float s, int m)
{
    if ((s > tv[KTOP-1]) || (s == tv[KTOP-1] && m < ti[KTOP-1])) {
        float cs = s; int ci = m;
#pragma unroll
        for (int q = 0; q < KTOP; ++q) {
            bool beats = (cs > tv[q]) || (cs == tv[q] && ci < ti[q]);
            if (beats) { float t0 = tv[q]; int t1 = ti[q];
                         tv[q] = cs; ti[q] = ci; cs = t0; ci = t1; }
        }
    }
}

// ---------------------------------------------------------------------------
// fp16 2-plane 3-product core on gload_lds layout (R15-proven): plane =
// 128 rows x 32 ushorts LINEAR; chunk q of row R at slot q ^ ((R>>1)&3).
// Wave tile 64x32. acc0 += Aa*Ba ; acc1 += Aa*BB + AB*Ba.
// ---------------------------------------------------------------------------
#define SPLIT3H_COMPUTE(Tb, wr, wc, lane, acc0, acc1)                           \
    {                                                                           \
        const int rr_ = (lane) & 15, q_ = (lane) >> 4;                          \
        const int Rb0_ = (wc) * 32 + rr_;                                       \
        const int Rb1_ = Rb0_ + 16;                                             \
        half8v ba0_ = *reinterpret_cast<const half8v*>(                         \
            &Tb[2 * 4096 + Rb0_ * 32 + ((q_ ^ ((Rb0_ >> 1) & 3)) << 3)]);       \
        half8v ba1_ = *reinterpret_cast<const half8v*>(                         \
            &Tb[2 * 4096 + Rb1_ * 32 + ((q_ ^ ((Rb1_ >> 1) & 3)) << 3)]);       \
        half8v bB0_ = *reinterpret_cast<const half8v*>(                         \
            &Tb[3 * 4096 + Rb0_ * 32 + ((q_ ^ ((Rb0_ >> 1) & 3)) << 3)]);       \
        half8v bB1_ = *reinterpret_cast<const half8v*>(                         \
            &Tb[3 * 4096 + Rb1_ * 32 + ((q_ ^ ((Rb1_ >> 1) & 3)) << 3)]);       \
        _Pragma("unroll")                                                       \
        for (int mi_ = 0; mi_ < 4; ++mi_) {                                     \
            const int Ra_ = (wr) * 64 + mi_ * 16 + rr_;                         \
            const int sw_ = (q_ ^ ((Ra_ >> 1) & 3)) << 3;                       \
            half8v aA_ = *reinterpret_cast<const half8v*>(&Tb[Ra_ * 32 + sw_]); \
            acc0[mi_][0] = __builtin_amdgcn_mfma_f32_16x16x32_f16(              \
                aA_, ba0_, acc0[mi_][0], 0, 0, 0);                              \
            acc0[mi_][1] = __builtin_amdgcn_mfma_f32_16x16x32_f16(              \
                aA_, ba1_, acc0[mi_][1], 0, 0, 0);                              \
            acc1[mi_][0] = __builtin_amdgcn_mfma_f32_16x16x32_f16(              \
                aA_, bB0_, acc1[mi_][0], 0, 0, 0);                              \
            acc1[mi_][1] = __builtin_amdgcn_mfma_f32_16x16x32_f16(              \
                aA_, bB1_, acc1[mi_][1], 0, 0, 0);                              \
        }                                                                       \
        _Pragma("unroll")                                                       \
        for (int mi_ = 0; mi_ < 4; ++mi_) {                                     \
            const int Ra_ = (wr) * 64 + mi_ * 16 + rr_;                         \
            const int sw_ = (q_ ^ ((Ra_ >> 1) & 3)) << 3;                       \
            half8v aB_ = *reinterpret_cast<const half8v*>(                      \
                &Tb[4096 + Ra_ * 32 + sw_]);                                    \
            acc1[mi_][0] = __builtin_amdgcn_mfma_f32_16x16x32_f16(              \
                aB_, ba0_, acc1[mi_][0], 0, 0, 0);                              \
            acc1[mi_][1] = __builtin_amdgcn_mfma_f32_16x16x32_f16(              \
                aB_, ba1_, acc1[mi_][1], 0, 0, 0);                              \
        }                                                                       \
    }

// stage one 32-k tile of one plane (this wave's half): 4 x gll16 (1KB each)
#define STAGE4(lb, koff)                                                        \
    {                                                                           \
        gll16(gp + goff + (koff), lb);                                          \
        gll16(gp + goff + (koff) + 16 * D_, (lb) + 512);                        \
        gll16(gp + goff + (koff) + 32 * D_, (lb) + 1024);                       \
        gll16(gp + goff + (koff) + 48 * D_, (lb) + 1536);                       \
    }

// ---------------------------------------------------------------------------
// qk_proj: MERGED Q and K projections. blocks [0,512) = Q, [512,1024) = K.
// SINGLE-buffer LDS (32KB) -> 4 blocks/CU resident -> grid fits in ONE round.
// 512 thr, 8 waves, BK=32, global_load_lds, 2 barriers/K-step.
// ---------------------------------------------------------------------------
__global__ __launch_bounds__(512, 2)
void qk_proj(const ushortT* __restrict__ A0, const ushortT* __restrict__ A1,
             const ushortT* __restrict__ QWa, const ushortT* __restrict__ QWB,
             const ushortT* __restrict__ KWa, const ushortT* __restrict__ KWB,
             const float* __restrict__ bq, const float* __restrict__ bk,
             ushortT* __restrict__ Qa, ushortT* __restrict__ QB,
             ushortT* __restrict__ Ka, ushortT* __restrict__ KB)
{
    __shared__ ushortT TT[16384];   // 32KB single buffer

    const int half = blockIdx.x >> 9;
    int lin = blockIdx.x & 511;
    lin = (lin & 7) * 64 + (lin >> 3);                    // XCD-chunked
    const int m0 = (lin >> 3) * 128;
    const int n0 = (lin & 7) * 128;

    const ushortT* B0 = half ? KWa : QWa;
    const ushortT* B1 = half ? KWB : QWB;
    const float* bias = half ? bk : bq;
    ushortT* Pa = half ? Ka : Qa;
    ushortT* Pb = half ? KB : QB;

    const int tid = threadIdx.x;
    const int wid = tid >> 6, lane = tid & 63;
    const int wr = wid >> 2, wc = wid & 3;

    const int pl = wid >> 1;
    const int hb = (wid & 1) * 64;
    const ushortT* gp = (pl == 0) ? A0 : (pl == 1) ? A1 : (pl == 2) ? B0 : B1;
    const int rbase = (pl < 2 ? m0 : n0) + hb + (lane >> 2);
    const int cg8 = ((lane & 3) ^ ((lane >> 3) & 3)) << 3;
    const size_t goff = (size_t)rbase * D_ + cg8;
    ushortT* lb0 = &TT[pl * 4096 + hb * 32];

    f32x4 acc0[4][2], acc1[4][2];
#pragma unroll
    for (int mi = 0; mi < 4; ++mi) {
        acc0[mi][0] = (f32x4){0,0,0,0}; acc0[mi][1] = (f32x4){0,0,0,0};
        acc1[mi][0] = (f32x4){0,0,0,0}; acc1[mi][1] = (f32x4){0,0,0,0};
    }

    for (int ks = 0; ks < 32; ++ks) {
        STAGE4(lb0, (size_t)ks * 32)
        __syncthreads();                 // drains vmcnt -> LDS tile ready
        __builtin_amdgcn_s_setprio(1);
        SPLIT3H_COMPUTE(TT, wr, wc, lane, acc0, acc1)
        __builtin_amdgcn_s_setprio(0);
        __syncthreads();                 // all reads done before next overwrite
    }

    const int r4 = (lane >> 4) * 4, cl = lane & 15;
#pragma unroll
    for (int mi = 0; mi < 4; ++mi)
#pragma unroll
        for (int ni = 0; ni < 2; ++ni) {
            int col = n0 + wc * 32 + ni * 16 + cl;
            float bb = bias[col];
#pragma unroll
            for (int r = 0; r < 4; ++r) {
                int row = m0 + wr * 64 + mi * 16 + r4 + r;
                float v = acc0[mi][ni][r] + INV2048 * acc1[mi][ni][r] + bb;
                halfT a = (halfT)v;  float r1 = v - (float)a;
                halfT b = (halfT)(r1 * 2048.0f);
                size_t o = (size_t)row * D_ + col;
                Pa[o] = h2u(a); Pb[o] = h2u(b);
            }
        }
}

// ---------------------------------------------------------------------------
// attn_scores_h: fp16 2-plane split scores + mask + pheromone + per-chunk
// top-8. SINGLE-buffer LDS (~41KB total) -> 3 blocks/CU -> 544 blocks fit in
// ONE round (768 slots). 512 thr, 8 waves, BK=32, gload_lds, 2 barriers/step.
// ---------------------------------------------------------------------------
__global__ __launch_bounds__(512, 2)
void attn_scores_h(const ushortT* __restrict__ Qa, const ushortT* __restrict__ QB,
                   const ushortT* __restrict__ Ka, const ushortT* __restrict__ KB,
                   const float* __restrict__ pher,
                   float* __restrict__ WV, int* __restrict__ WI)
{
    __shared__ ushortT TT[16384];   // 32KB single buffer
    __shared__ float Ps[128];
    __shared__ float PV[32 * 4 * 8];
    __shared__ int   PI[32 * 4 * 8];
    float* MV = reinterpret_cast<float*>(&TT[0]);                 // [32][128]
    int*   MI = reinterpret_cast<int*>((char*)&TT[0] + 16384);    // [32][128]

    int lin = blockIdx.y * 136 + blockIdx.x;              // 0..543
    lin = (lin & 7) * 68 + (lin >> 3);                    // XCD-chunked, 544=8*68
    const int b = lin / 136;
    const int xy = lin - b * 136;
    int g = 0;
    while ((g + 1) * (g + 2) / 2 <= xy) ++g;
    const int ch = xy - g * (g + 1) / 2;
    const int n0 = g * 128;
    const int m0 = ch * 128;
    const size_t bN = (size_t)b * N_;

    const int tid = threadIdx.x;
    const int wid = tid >> 6, lane = tid & 63;
    const int wr = wid >> 2, wc = wid & 3;

    if (tid < 128) Ps[tid] = pher[bN + m0 + tid];

    const int pl = wid >> 1;
    const int hb = (wid & 1) * 64;
    const ushortT* gp = (pl == 0) ? Qa : (pl == 1) ? QB : (pl == 2) ? Ka : KB;
    const size_t rbase = bN + (pl < 2 ? n0 : m0) + hb + (lane >> 2);
    const int cg8 = ((lane & 3) ^ ((lane >> 3) & 3)) << 3;
    const size_t goff = rbase * (size_t)D_ + cg8;
    ushortT* lb0 = &TT[pl * 4096 + hb * 32];

    f32x4 acc0[4][2], acc1[4][2];
#pragma unroll
    for (int mi = 0; mi < 4; ++mi) {
        acc0[mi][0] = (f32x4){0,0,0,0}; acc0[mi][1] = (f32x4){0,0,0,0};
        acc1[mi][0] = (f32x4){0,0,0,0}; acc1[mi][1] = (f32x4){0,0,0,0};
    }

    for (int ks = 0; ks < 32; ++ks) {
        STAGE4(lb0, (size_t)ks * 32)
        __syncthreads();                 // drains vmcnt -> LDS tile ready
        __builtin_amdgcn_s_setprio(1);
        SPLIT3H_COMPUTE(TT, wr, wc, lane, acc0, acc1)
        __builtin_amdgcn_s_setprio(0);
        __syncthreads();                 // all reads done before next overwrite
    }

    // ---- fold to per-row top-8: 4 passes of 32 rows ----
    const int r4 = (lane >> 4) * 4, cl = lane & 15;
    for (int p = 0; p < 4; ++p) {
        __syncthreads();                       // TT/MV consumers done
        if (wr == (p >> 1)) {
#pragma unroll
            for (int mi2 = 0; mi2 < 2; ++mi2) {
                const int mi = (p & 1) * 2 + mi2;
#pragma unroll
                for (int ni = 0; ni < 2; ++ni) {
                    int col = wc * 32 + ni * 16 + cl;
                    int m = m0 + col;
#pragma unroll
                    for (int r = 0; r < 4; ++r) {
                        int rloc = mi2 * 16 + r4 + r;
                        int n = n0 + p * 32 + rloc;
                        bool ok = (m <= n);
                        float sc = acc0[mi][ni][r] + INV2048 * acc1[mi][ni][r];
                        MV[rloc * 128 + col] = ok ? (sc * SCALE_ + ALPHA_ * Ps[col])
                                                  : -INFINITY;
                        MI[rloc * 128 + col] = ok ? m : 0x7fffffff;
                    }
                }
            }
        }
        __syncthreads();
        if (tid < 128) {                       // partial top-8 over a 32-col quarter
            const int row = tid >> 2, q4 = tid & 3;
            float tv[KTOP]; int ti[KTOP];
#pragma unroll
            for (int j = 0; j < KTOP; ++j) { tv[j] = -INFINITY; ti[j] = 0x7fffffff; }
            for (int j = 0; j < 32; ++j) {
                float s2 = MV[row * 128 + q4 * 32 + j];
                if (s2 == -INFINITY) continue;
                topk_insert(tv, ti, s2, MI[row * 128 + q4 * 32 + j]);
            }
#pragma unroll
            for (int j = 0; j < KTOP; ++j) {
                PV[(row * 4 + q4) * 8 + j] = tv[j];
                PI[(row * 4 + q4) * 8 + j] = ti[j];
            }
        }
        __syncthreads();
        if (tid < 32) {                        // merge 4 partials -> chunk top-8
            float tv[KTOP]; int ti[KTOP];
#pragma unroll
            for (int j = 0; j < KTOP; ++j) { tv[j] = -INFINITY; ti[j] = 0x7fffffff; }
            for (int i = 0; i < 32; ++i) {
                float s2 = PV[tid * 32 + i];
                if (s2 == -INFINITY) continue;
                topk_insert(tv, ti, s2, PI[tid * 32 + i]);
            }
            int n = n0 + p * 32 + tid;
            size_t base = ((bN + n) * NCH + ch) * 8;
#pragma unroll
            for (int j = 0; j < KTOP; ++j) { WV[base + j] = tv[j]; WI[base + j] = ti[j]; }
        }
    }
}

// ---------------------------------------------------------------------------
// attn_merge: merge <=16 chunk lists -> top-8 -> softmax -> gather fp16 V ->
// CCb right half (fp16). Grid 2048 blocks, 4 rows each.
// ---------------------------------------------------------------------------
__global__ __launch_bounds__(256)
void attn_merge(const float* __restrict__ WV, const int* __restrict__ WI,
                const ushortT* __restrict__ V, ushortT* __restrict__ CCb)
{
    __shared__ float CV[4][128];
    __shared__ int   CI[4][128];
    __shared__ float Pp[4][KTOP];
    __shared__ int   Pi[4][KTOP];

    const int tid  = threadIdx.x;
    const int wv   = tid >> 6;
    const int lane = tid & 63;
    const int rid  = blockIdx.x * 4 + wv;
    const int b    = rid >> 11;
    const int n    = rid & (N_ - 1);
    const int ncand = ((n >> 7) + 1) * 8;
    const size_t cbase = (size_t)rid * (NCH * 8);

#pragma unroll
    for (int t = 0; t < 2; ++t) {
        int i = lane + t * 64;
        if (i < ncand) { CV[wv][i] = WV[cbase + i]; CI[wv][i] = WI[cbase + i]; }
        else           { CV[wv][i] = -INFINITY;     CI[wv][i] = 0x7fffffff;   }
    }
    __syncthreads();

    if (lane == 0) {
        float tv[KTOP]; int ti[KTOP];
#pragma unroll
        for (int j = 0; j < KTOP; ++j) { tv[j] = -INFINITY; ti[j] = 0x7fffffff; }
        for (int i = 0; i < 128; ++i) {
            float s = CV[wv][i];
            if (s == -INFINITY) continue;
            topk_insert(tv, ti, s, CI[wv][i]);
        }
        float mx = tv[0];
        float e[KTOP]; float sum = 0.f;
#pragma unroll
        for (int j = 0; j < KTOP; ++j) {
            e[j] = (tv[j] == -INFINITY) ? 0.f : __expf(tv[j] - mx);
            sum += e[j];
        }
        float inv = 1.f / sum;
#pragma unroll
        for (int j = 0; j < KTOP; ++j) {
            Pp[wv][j] = e[j] * inv;
            Pi[wv][j] = (tv[j] == -INFINITY) ? 0 : ti[j];
        }
    }
    __syncthreads();

    const size_t vbase = (size_t)b * N_ * D_;
#pragma unroll
    for (int it = 0; it < 2; ++it) {
        int c8 = (it * 64 + lane) * 8;
        float o[8];
#pragma unroll
        for (int u = 0; u < 8; ++u) o[u] = 0.f;
#pragma unroll
        for (int j = 0; j < KTOP; ++j) {
            float p = Pp[wv][j];
            ushort4 v0 = *reinterpret_cast<const ushort4*>(
                &V[vbase + (size_t)Pi[wv][j] * D_ + c8]);
            ushort4 v1 = *reinterpret_cast<const ushort4*>(
                &V[vbase + (size_t)Pi[wv][j] * D_ + c8 + 4]);
            o[0] = fmaf(p, uh2f(v0.x), o[0]); o[1] = fmaf(p, uh2f(v0.y), o[1]);
            o[2] = fmaf(p, uh2f(v0.z), o[2]); o[3] = fmaf(p, uh2f(v0.w), o[3]);
            o[4] = fmaf(p, uh2f(v1.x), o[4]); o[5] = fmaf(p, uh2f(v1.y), o[5]);
            o[6] = fmaf(p, uh2f(v1.z), o[6]); o[7] = fmaf(p, uh2f(v1.w), o[7]);
        }
        ushort4 ob0 = {h2u((halfT)o[0]), h2u((halfT)o[1]), h2u((halfT)o[2]), h2u((halfT)o[3])};
        ushort4 ob1 = {h2u((halfT)o[4]), h2u((halfT)o[5]), h2u((halfT)o[6]), h2u((halfT)o[7])};
        *reinterpret_cast<ushort4*>(&CCb[(size_t)rid * 2048 + 1024 + c8]) = ob0;
        *reinterpret_cast<ushort4*>(&CCb[(size_t)rid * 2048 + 1024 + c8 + 4]) = ob1;
    }
}

// ---------------------------------------------------------------------------
extern "C" void kernel_launch(void* const* d_in, const int* in_sizes, int n_in,
                              void* d_out, int out_size, void* d_ws, size_t ws_size,
                              hipStream_t stream)
{
    const float* mu   = (const float*)d_in[0];
    const float* pher = (const float*)d_in[1];
    const float* Wq   = (const float*)d_in[2];
    const float* bq   = (const float*)d_in[3];
    const float* Wk   = (const float*)d_in[4];
    const float* bk   = (const float*)d_in[5];
    const float* Wv   = (const float*)d_in[6];
    const float* bv   = (const float*)d_in[7];
    const float* Wm1  = (const float*)d_in[8];
    const float* bm1  = (const float*)d_in[9];
    const float* Wm2  = (const float*)d_in[10];
    const float* bm2  = (const float*)d_in[11];
    const float* Wo   = (const float*)d_in[12];
    const float* bo   = (const float*)d_in[13];
    float* out = (float*)d_out;
    float* ws  = (float*)d_ws;

    const size_t SZ  = (size_t)B_ * N_ * D_;    // 8388608 floats
    const size_t MEG = 1024 * 1024;             // floats
    const int M = B_ * N_;                      // 8192

    // ---- workspace map (float units). Vb16 disjoint from Sb (R18 fix). ----
    ushortT* CCb  = (ushortT*)ws;                         // [8192][2048] fp16 [0,SZ)
    float*   PF   = ws + SZ;                              // [SZ,3SZ) f32 pre-act
    ushortT* Qa   = (ushortT*)(ws + SZ);                  // overlay PF (after silu)
    ushortT* QB   = Qa + SZ;
    ushortT* Ka   = (ushortT*)(ws + 2 * SZ);
    ushortT* KB   = Ka + SZ;
    ushortT* mu_a = (ushortT*)(ws + 3 * SZ);              // [3SZ,3.5SZ)
    ushortT* mu_B = mu_a + SZ;                            // [3.5SZ,4SZ)
    ushortT* Sb   = (ushortT*)(ws + 4 * SZ);              // [4SZ,4SZ+4MEG) fp16 S
    float*   WVb  = (float*)(ws + 4 * SZ);                // overlay Sb (after local gemm)
    int*     WIb  = (int*)(WVb + MEG);
    ushortT* Vb16 = (ushortT*)(ws + 4 * SZ + 4 * MEG);    // disjoint from Sb
    ushortT* U    = (ushortT*)(ws + 4 * SZ + 8 * MEG);    // weights, 10M ushorts
    ushortT* WtF  = U;                   // [2048][1024] fused Wm1^T = 2M ush
    ushortT* Wt_m2 = U + 2 * MEG;        // [1024][1024] = 1M ush
    ushortT* Wt_v  = U + 3 * MEG;        // 1M ush
    ushortT* WqT_a = U + 4 * MEG;        ushortT* WqT_B = U + 5 * MEG;
    ushortT* WkT_a = U + 6 * MEG;        ushortT* WkT_B = U + 7 * MEG;
    ushortT* Wt_o  = U + 8 * MEG;        // [1024][2048] = 2M ush

    dim3 blk256(256), blk512(512);
    dim3 gD(8, 64);

    // 1. ALL prep: mu split + 7 weight transposes (one launch)
    hipLaunchKernelGGL(prep_all, dim3(16384), blk256, 0, stream,
                       mu, Wm1, Wm2, Wv, Wo, Wq, Wk,
                       mu_a, mu_B, WtF, Wt_m2, Wt_v, Wt_o,
                       WqT_a, WqT_B, WkT_a, WkT_B);
    // 2. PF pre-act gemm + V gemm (merged, 1536 blocks)
    hipLaunchKernelGGL(gemm_pf_v, dim3(1536), blk256, 0, stream,
                       mu_a, WtF, Wt_v, bv, PF, Vb16);
    // 3. silu-mean (consumes PF; adds bm1 inside) -> Sb. PF dead after.
    hipLaunchKernelGGL(silu_mean, dim3(SZ / 4 / 256), blk256, 0, stream, PF, bm1, Sb);
    // 4. local msgs -> CCb left half (consumes Sb)
    hipLaunchKernelGGL((mfma_gemm_h<1>), gD, blk256, 0, stream,
                       Sb, D_, Wt_m2, D_, bm2, (void*)CCb, 2 * D_, D_);
    // 5. Q + K projections (merged; outputs overlay the now-dead PF region)
    hipLaunchKernelGGL(qk_proj, dim3(1024), blk512, 0, stream,
                       mu_a, mu_B, WqT_a, WqT_B, WkT_a, WkT_B,
                       bq, bk, Qa, QB, Ka, KB);
    // 6. scores + per-chunk top-8 (WVb/WIb overlay dead Sb)
    hipLaunchKernelGGL(attn_scores_h, dim3(136, B_), blk512, 0, stream,
                       Qa, QB, Ka, KB, pher, WVb, WIb);
    // 7. merge + softmax + V gather -> CCb right half
    hipLaunchKernelGGL(attn_merge, dim3(M / 4), blk256, 0, stream, WVb, WIb, Vb16, CCb);
    // 8. out = CCb @ Wo + bo (fp16 MFMA, K=2048, f32 out)
    hipLaunchKernelGGL((mfma_gemm_h<0>), gD, blk256, 0, stream,
                       CCb, 2 * D_, Wt_o, 2048, bo, (void*)out, D_, 2 * D_);

    (void)in_sizes; (void)n_in; (void)out_size; (void)ws_size;
}

// Round 20
// 739.062 us; speedup vs baseline: 1.0009x; 1.0009x over previous
//
#include <hip/hip_runtime.h>
#include <hip/hip_bf16.h>
#include <math.h>

#define B_ 4
#define N_ 2048
#define D_ 1024
#define WIN_ 4
#define KTOP 8
#define ALPHA_ 0.3f
#define SCALE_ (1.0f/32.0f)
#define NCH 16          // N_/128 col chunks
#define INV2048 0.00048828125f

typedef unsigned short ushortT;
typedef _Float16 halfT;
typedef __attribute__((ext_vector_type(8))) _Float16 half8v;  // 8 fp16 (4 VGPR)
typedef __attribute__((ext_vector_type(4))) float f32x4;

__device__ inline ushortT h2u(halfT h){ union{halfT h; ushortT u;} x; x.h=h; return x.u; }
__device__ inline halfT  u2h(ushortT u){ union{halfT h; ushortT u;} x; x.u=u; return x.h; }
__device__ inline float  uh2f(ushortT u){ return (float)u2h(u); }

// async global->LDS, 16B per lane (dest = wave-uniform base + lane*16)
__device__ __forceinline__ void gll16(const ushortT* g, ushortT* l) {
    __builtin_amdgcn_global_load_lds(
        (const __attribute__((address_space(1))) void*)g,
        (__attribute__((address_space(3))) void*)l, 16, 0, 0);
}

// ---------------------------------------------------------------------------
// prep_all: ONE launch for all input prep.
// ---------------------------------------------------------------------------
__global__ __launch_bounds__(256)
void prep_all(const float* __restrict__ mu, const float* __restrict__ Wm1,
              const float* __restrict__ Wm2, const float* __restrict__ Wv,
              const float* __restrict__ Wo, const float* __restrict__ Wq,
              const float* __restrict__ Wk,
              ushortT* __restrict__ mu_a, ushortT* __restrict__ mu_B,
              ushortT* __restrict__ WtF, ushortT* __restrict__ Wt_m2,
              ushortT* __restrict__ Wt_v, ushortT* __restrict__ Wt_o,
              ushortT* __restrict__ WqT_a, ushortT* __restrict__ WqT_B,
              ushortT* __restrict__ WkT_a, ushortT* __restrict__ WkT_B)
{
    const int bid = blockIdx.x;
    if (bid < 8192) {                       // ---- split2_mu ----
        size_t base = ((size_t)bid * 256 + threadIdx.x) * 4;
        float4 v = *reinterpret_cast<const float4*>(&mu[base]);
        float vv[4] = {v.x, v.y, v.z, v.w};
        ushort4 pa, pb;
#pragma unroll
        for (int j = 0; j < 4; ++j) {
            float f = vv[j];
            halfT a = (halfT)f;  float r = f - (float)a;
            halfT b = (halfT)(r * 2048.0f);
            ((ushortT*)&pa)[j] = h2u(a); ((ushortT*)&pb)[j] = h2u(b);
        }
        *reinterpret_cast<ushort4*>(&mu_a[base]) = pa;
        *reinterpret_cast<ushort4*>(&mu_B[base]) = pb;
        return;
    }
    // ---- transposes ----
    __shared__ float t[32][33];
    int b = bid - 8192;
    const float* W; ushortT* Pa; ushortT* Pb = nullptr;
    int K, lb, split = 0;
    if (b < 1024)      { W = Wm1;                       Pa = WtF;                     K = 1024; lb = b; }
    else if (b < 2048) { W = Wm1 + (size_t)1024 * 1024; Pa = WtF + (size_t)1024*1024; K = 1024; lb = b - 1024; }
    else if (b < 3072) { W = Wm2;  Pa = Wt_m2; K = 1024; lb = b - 2048; }
    else if (b < 4096) { W = Wv;   Pa = Wt_v;  K = 1024; lb = b - 3072; }
    else if (b < 6144) { W = Wo;   Pa = Wt_o;  K = 2048; lb = b - 4096; }
    else if (b < 7168) { W = Wq;   Pa = WqT_a; Pb = WqT_B; K = 1024; lb = b - 6144; split = 1; }
    else               { W = Wk;   Pa = WkT_a; Pb = WkT_B; K = 1024; lb = b - 7168; split = 1; }
    const int Nn = 1024;
    const int k0 = (K == 2048) ? (lb & 63) * 32 : (lb & 31) * 32;
    const int n0 = (K == 2048) ? (lb >> 6) * 32 : (lb >> 5) * 32;
    const int tx = threadIdx.x & 31, ty8 = threadIdx.x >> 5;
#pragma unroll
    for (int p = 0; p < 4; ++p) {
        int kk = p * 8 + ty8;
        t[kk][tx] = W[(size_t)(k0 + kk) * Nn + n0 + tx];
    }
    __syncthreads();
#pragma unroll
    for (int p = 0; p < 4; ++p) {
        int nn = p * 8 + ty8;
        float f = t[tx][nn];
        size_t o = (size_t)(n0 + nn) * K + k0 + tx;
        if (split) {
            halfT a = (halfT)f;  float r = f - (float)a;
            halfT bb = (halfT)(r * 2048.0f);
            Pa[o] = h2u(a); Pb[o] = h2u(bb);
        } else {
            Pa[o] = h2u((halfT)f);
        }
    }
}

// ---------------------------------------------------------------------------
// fp16 MFMA GEMM core (256 thr, 4 waves, 64x64/wave) — proven.
// ---------------------------------------------------------------------------
__device__ __forceinline__ void gemm_core_h(
    const ushortT* __restrict__ A, int lda, const ushortT* __restrict__ Bt, int ldb,
    const float* __restrict__ bias, void* __restrict__ Cout, int ldc, int K,
    int m0, int n0, int outHalf, ushortT* AsL, ushortT* BsL)
{
    const int tid = threadIdx.x;
    const int w = tid >> 6, lane = tid & 63;
    const int wr = w >> 1, wc = w & 1;

    f32x4 acc[4][4];
#pragma unroll
    for (int mi = 0; mi < 4; ++mi)
#pragma unroll
        for (int ni = 0; ni < 4; ++ni) acc[mi][ni] = (f32x4){0.f, 0.f, 0.f, 0.f};

    for (int k0 = 0; k0 < K; k0 += 64) {
#pragma unroll
        for (int it = 0; it < 4; ++it) {
            int idx = tid + it * 256;        // 0..1023
            int row = idx >> 3, c = idx & 7;
            int4 va = *reinterpret_cast<const int4*>(&A[(size_t)(m0 + row) * lda + k0 + c * 8]);
            *reinterpret_cast<int4*>(&AsL[row * 72 + c * 8]) = va;
            int4 vb = *reinterpret_cast<const int4*>(&Bt[(size_t)(n0 + row) * ldb + k0 + c * 8]);
            *reinterpret_cast<int4*>(&BsL[row * 72 + c * 8]) = vb;
        }
        __syncthreads();
#pragma unroll
        for (int kh = 0; kh < 2; ++kh) {
            const int ko = kh * 32 + (lane >> 4) * 8;
            const int rr = lane & 15;
            half8v af[4], bf[4];
#pragma unroll
            for (int mi = 0; mi < 4; ++mi)
                af[mi] = *reinterpret_cast<const half8v*>(&AsL[(wr * 64 + mi * 16 + rr) * 72 + ko]);
#pragma unroll
            for (int ni = 0; ni < 4; ++ni)
                bf[ni] = *reinterpret_cast<const half8v*>(&BsL[(wc * 64 + ni * 16 + rr) * 72 + ko]);
#pragma unroll
            for (int mi = 0; mi < 4; ++mi)
#pragma unroll
                for (int ni = 0; ni < 4; ++ni)
                    acc[mi][ni] = __builtin_amdgcn_mfma_f32_16x16x32_f16(
                        af[mi], bf[ni], acc[mi][ni], 0, 0, 0);
        }
        __syncthreads();
    }

    const int r4 = (lane >> 4) * 4, cl = lane & 15;
#pragma unroll
    for (int mi = 0; mi < 4; ++mi)
#pragma unroll
        for (int ni = 0; ni < 4; ++ni) {
            int row = m0 + wr * 64 + mi * 16 + r4;
            int col = n0 + wc * 64 + ni * 16 + cl;
            float bb = bias ? bias[col] : 0.f;
#pragma unroll
            for (int r = 0; r < 4; ++r) {
                float v = acc[mi][ni][r] + bb;
                if (outHalf)
                    ((ushortT*)Cout)[(size_t)(row + r) * ldc + col] = h2u((halfT)v);
                else
                    ((float*)Cout)[(size_t)(row + r) * ldc + col] = v;
            }
        }
}

template<int OUT_HALF>
__global__ __launch_bounds__(256)
void mfma_gemm_h(const ushortT* __restrict__ A, int lda,
                 const ushortT* __restrict__ Bt, int ldb,
                 const float* __restrict__ bias,
                 void* __restrict__ Cout, int ldc, int K)
{
    __shared__ ushortT AsL[128 * 72];
    __shared__ ushortT BsL[128 * 72];
    gemm_core_h(A, lda, Bt, ldb, bias, Cout, ldc, K,
                blockIdx.y * 128, blockIdx.x * 128, OUT_HALF, AsL, BsL);
}

// merged: blocks [0,1024) = PF pre-act gemm (Nc=2048, f32 out);
//         blocks [1024,1536) = V gemm (fp16 out)
__global__ __launch_bounds__(256)
void gemm_pf_v(const ushortT* __restrict__ mu_a,
               const ushortT* __restrict__ WtF, const ushortT* __restrict__ Wt_v,
               const float* __restrict__ bv,
               float* __restrict__ PF, ushortT* __restrict__ Vb16)
{
    __shared__ ushortT AsL[128 * 72];
    __shared__ ushortT BsL[128 * 72];
    const int bid = blockIdx.x;
    if (bid < 1024) {
        gemm_core_h(mu_a, D_, WtF, D_, (const float*)nullptr, (void*)PF, 2 * D_, D_,
                    (bid >> 4) * 128, (bid & 15) * 128, 0, AsL, BsL);
    } else {
        const int b2 = bid - 1024;
        gemm_core_h(mu_a, D_, Wt_v, D_, bv, (void*)Vb16, D_, D_,
                    (b2 >> 3) * 128, (b2 & 7) * 128, 1, AsL, BsL);
    }
}

// ---------------------------------------------------------------------------
// silu_mean (fused pre-act consumer), fp16 out.
// ---------------------------------------------------------------------------
__global__ __launch_bounds__(256)
void silu_mean(const float* __restrict__ P, const float* __restrict__ bm1,
               ushortT* __restrict__ Sb)
{
    size_t idx4 = (size_t)blockIdx.x * blockDim.x + threadIdx.x;
    size_t base = idx4 << 2;                 // logical [row][1024]
    int row = (int)(base >> 10);
    int col = (int)(base & 1023);
    int n = row & (N_ - 1);
    float4 a = *reinterpret_cast<const float4*>(&P[(size_t)row * 2048 + col]);
    float4 bb = *reinterpret_cast<const float4*>(&bm1[col]);
    a.x += bb.x; a.y += bb.y; a.z += bb.z; a.w += bb.w;
    float sx = 0.f, sy = 0.f, sz = 0.f, sw = 0.f;
#pragma unroll
    for (int w = 1; w <= WIN_; ++w) {
        float xx = a.x, xy = a.y, xz = a.z, xw = a.w;
        if (n >= w) {
            const float4 nb = *reinterpret_cast<const float4*>(
                &P[(size_t)(row - w) * 2048 + 1024 + col]);
            xx += nb.x; xy += nb.y; xz += nb.z; xw += nb.w;
        }
        sx += xx / (1.f + __expf(-xx));
        sy += xy / (1.f + __expf(-xy));
        sz += xz / (1.f + __expf(-xz));
        sw += xw / (1.f + __expf(-xw));
    }
    ushort4 o = {h2u((halfT)(sx * 0.25f)), h2u((halfT)(sy * 0.25f)),
                 h2u((halfT)(sz * 0.25f)), h2u((halfT)(sw * 0.25f))};
    *reinterpret_cast<ushort4*>(&Sb[base]) = o;
}

// ---------------------------------------------------------------------------
__device__ inline void topk_insert(float (&tv)[KTOP], int (&ti)[KTOP], float s, int m)
{
    if ((s > tv[KTOP-1]) || (s == tv[KTOP-1] && m < ti[KTOP-1])) {
        float cs = s; int ci = m;
#pragma unroll
        for (int q = 0; q < KTOP; ++q) {
            bool beats = (cs > tv[q]) || (cs == tv[q] && ci < ti[q]);
            if (beats) { float t0 = tv[q]; int t1 = ti[q];
                         tv[q] = cs; ti[q] = ci; cs = t0; ci = t1; }
        }
    }
}

// ---------------------------------------------------------------------------
// fp16 2-plane 3-product core on gload_lds layout (proven).
// ---------------------------------------------------------------------------
#define SPLIT3H_COMPUTE(Tb, wr, wc, lane, acc0, acc1)                           \
    {                                                                           \
        const int rr_ = (lane) & 15, q_ = (lane) >> 4;                          \
        const int Rb0_ = (wc) * 32 + rr_;                                       \
        const int Rb1_ = Rb0_ + 16;                                             \
        half8v ba0_ = *reinterpret_cast<const half8v*>(                         \
            &Tb[2 * 4096 + Rb0_ * 32 + ((q_ ^ ((Rb0_ >> 1) & 3)) << 3)]);       \
        half8v ba1_ = *reinterpret_cast<const half8v*>(                         \
            &Tb[2 * 4096 + Rb1_ * 32 + ((q_ ^ ((Rb1_ >> 1) & 3)) << 3)]);       \
        half8v bB0_ = *reinterpret_cast<const half8v*>(                         \
            &Tb[3 * 4096 + Rb0_ * 32 + ((q_ ^ ((Rb0_ >> 1) & 3)) << 3)]);       \
        half8v bB1_ = *reinterpret_cast<const half8v*>(                         \
            &Tb[3 * 4096 + Rb1_ * 32 + ((q_ ^ ((Rb1_ >> 1) & 3)) << 3)]);       \
        _Pragma("unroll")                                                       \
        for (int mi_ = 0; mi_ < 4; ++mi_) {                                     \
            const int Ra_ = (wr) * 64 + mi_ * 16 + rr_;                         \
            const int sw_ = (q_ ^ ((Ra_ >> 1) & 3)) << 3;                       \
            half8v aA_ = *reinterpret_cast<const half8v*>(&Tb[Ra_ * 32 + sw_]); \
            acc0[mi_][0] = __builtin_amdgcn_mfma_f32_16x16x32_f16(              \
                aA_, ba0_, acc0[mi_][0], 0, 0, 0);                              \
            acc0[mi_][1] = __builtin_amdgcn_mfma_f32_16x16x32_f16(              \
                aA_, ba1_, acc0[mi_][1], 0, 0, 0);                              \
            acc1[mi_][0] = __builtin_amdgcn_mfma_f32_16x16x32_f16(              \
                aA_, bB0_, acc1[mi_][0], 0, 0, 0);                              \
            acc1[mi_][1] = __builtin_amdgcn_mfma_f32_16x16x32_f16(              \
                aA_, bB1_, acc1[mi_][1], 0, 0, 0);                              \
        }                                                                       \
        _Pragma("unroll")                                                       \
        for (int mi_ = 0; mi_ < 4; ++mi_) {                                     \
            const int Ra_ = (wr) * 64 + mi_ * 16 + rr_;                         \
            const int sw_ = (q_ ^ ((Ra_ >> 1) & 3)) << 3;                       \
            half8v aB_ = *reinterpret_cast<const half8v*>(                      \
                &Tb[4096 + Ra_ * 32 + sw_]);                                    \
            acc1[mi_][0] = __builtin_amdgcn_mfma_f32_16x16x32_f16(              \
                aB_, ba0_, acc1[mi_][0], 0, 0, 0);                              \
            acc1[mi_][1] = __builtin_amdgcn_mfma_f32_16x16x32_f16(              \
                aB_, ba1_, acc1[mi_][1], 0, 0, 0);                              \
        }                                                                       \
    }

// stage one 32-k tile of one plane (this wave's half): 4 x gll16 (1KB each)
#define STAGE4(lb, koff)                                                        \
    {                                                                           \
        gll16(gp + goff + (koff), lb);                                          \
        gll16(gp + goff + (koff) + 16 * D_, (lb) + 512);                        \
        gll16(gp + goff + (koff) + 32 * D_, (lb) + 1024);                       \
        gll16(gp + goff + (koff) + 48 * D_, (lb) + 1536);                       \
    }

// ---------------------------------------------------------------------------
// mid_all: blocks [0,1024) = MERGED Q/K projections (R19-proven body);
//          blocks [1024,1536) = local-message GEMM (Sb @ Wt_m2 -> CCb left),
//          512-thread variant of the proven core: 8 waves, 64x32 wave tile,
//          identical per-element k-order -> bit-identical output.
// These two tasks are data-independent; merging overlaps them on the device.
// ---------------------------------------------------------------------------
__global__ __launch_bounds__(512, 2)
void mid_all(const ushortT* __restrict__ A0, const ushortT* __restrict__ A1,
             const ushortT* __restrict__ QWa, const ushortT* __restrict__ QWB,
             const ushortT* __restrict__ KWa, const ushortT* __restrict__ KWB,
             const float* __restrict__ bq, const float* __restrict__ bk,
             ushortT* __restrict__ Qa, ushortT* __restrict__ QB,
             ushortT* __restrict__ Ka, ushortT* __restrict__ KB,
             const ushortT* __restrict__ Sb, const ushortT* __restrict__ Wt_m2,
             const float* __restrict__ bm2, ushortT* __restrict__ CCb)
{
    __shared__ ushortT SMEM[18432];   // union: qk 16384 | gemm AsL 9216 + BsL 9216

    const int tid = threadIdx.x;
    const int wid = tid >> 6, lane = tid & 63;

    if (blockIdx.x >= 1024) {
        // ---------- local-message GEMM: 128x128 tile, 8 waves, 64x32/wave ----
        const int t = blockIdx.x - 1024;          // 0..511
        const int m0 = (t >> 3) * 128;
        const int n0 = (t & 7) * 128;
        ushortT* AsL = SMEM;                      // 128*72
        ushortT* BsL = SMEM + 9216;
        const int wr = wid >> 2, wc = wid & 3;

        f32x4 acc[4][2];
#pragma unroll
        for (int mi = 0; mi < 4; ++mi) { acc[mi][0] = (f32x4){0,0,0,0}; acc[mi][1] = (f32x4){0,0,0,0}; }

        for (int k0 = 0; k0 < D_; k0 += 64) {
#pragma unroll
            for (int it = 0; it < 2; ++it) {
                int idx = tid + it * 512;         // 0..1023
                int row = idx >> 3, c = idx & 7;
                int4 va = *reinterpret_cast<const int4*>(&Sb[(size_t)(m0 + row) * D_ + k0 + c * 8]);
                *reinterpret_cast<int4*>(&AsL[row * 72 + c * 8]) = va;
                int4 vb = *reinterpret_cast<const int4*>(&Wt_m2[(size_t)(n0 + row) * D_ + k0 + c * 8]);
                *reinterpret_cast<int4*>(&BsL[row * 72 + c * 8]) = vb;
            }
            __syncthreads();
#pragma unroll
            for (int kh = 0; kh < 2; ++kh) {
                const int ko = kh * 32 + (lane >> 4) * 8;
                const int rr = lane & 15;
                half8v af[4], bf[2];
#pragma unroll
                for (int mi = 0; mi < 4; ++mi)
                    af[mi] = *reinterpret_cast<const half8v*>(&AsL[(wr * 64 + mi * 16 + rr) * 72 + ko]);
#pragma unroll
                for (int ni = 0; ni < 2; ++ni)
                    bf[ni] = *reinterpret_cast<const half8v*>(&BsL[(wc * 32 + ni * 16 + rr) * 72 + ko]);
#pragma unroll
                for (int mi = 0; mi < 4; ++mi)
#pragma unroll
                    for (int ni = 0; ni < 2; ++ni)
                        acc[mi][ni] = __builtin_amdgcn_mfma_f32_16x16x32_f16(
                            af[mi], bf[ni], acc[mi][ni], 0, 0, 0);
            }
            __syncthreads();
        }

        const int r4 = (lane >> 4) * 4, cl = lane & 15;
#pragma unroll
        for (int mi = 0; mi < 4; ++mi)
#pragma unroll
            for (int ni = 0; ni < 2; ++ni) {
                int col = n0 + wc * 32 + ni * 16 + cl;
                float bb = bm2[col];
#pragma unroll
                for (int r = 0; r < 4; ++r) {
                    int row = m0 + wr * 64 + mi * 16 + r4 + r;
                    CCb[(size_t)row * 2048 + col] = h2u((halfT)(acc[mi][ni][r] + bb));
                }
            }
        return;
    }

    // ---------- Q/K projections (R19-proven single-buffer gload_lds body) ----
    ushortT* TT = SMEM;                           // 16384 ushorts
    const int half = blockIdx.x >> 9;
    int lin = blockIdx.x & 511;
    lin = (lin & 7) * 64 + (lin >> 3);            // XCD-chunked
    const int m0 = (lin >> 3) * 128;
    const int n0 = (lin & 7) * 128;

    const ushortT* B0 = half ? KWa : QWa;
    const ushortT* B1 = half ? KWB : QWB;
    const float* bias = half ? bk : bq;
    ushortT* Pa = half ? Ka : Qa;
    ushortT* Pb = half ? KB : QB;

    const int wr = wid >> 2, wc = wid & 3;
    const int pl = wid >> 1;
    const int hb = (wid & 1) * 64;
    const ushortT* gp = (pl == 0) ? A0 : (pl == 1) ? A1 : (pl == 2) ? B0 : B1;
    const int rbase = (pl < 2 ? m0 : n0) + hb + (lane >> 2);
    const int cg8 = ((lane & 3) ^ ((lane >> 3) & 3)) << 3;
    const size_t goff = (size_t)rbase * D_ + cg8;
    ushortT* lb0 = &TT[pl * 4096 + hb * 32];

    f32x4 acc0[4][2], acc1[4][2];
#pragma unroll
    for (int mi = 0; mi < 4; ++mi) {
        acc0[mi][0] = (f32x4){0,0,0,0}; acc0[mi][1] = (f32x4){0,0,0,0};
        acc1[mi][0] = (f32x4){0,0,0,0}; acc1[mi][1] = (f32x4){0,0,0,0};
    }

    for (int ks = 0; ks < 32; ++ks) {
        STAGE4(lb0, (size_t)ks * 32)
        __syncthreads();
        __builtin_amdgcn_s_setprio(1);
        SPLIT3H_COMPUTE(TT, wr, wc, lane, acc0, acc1)
        __builtin_amdgcn_s_setprio(0);
        __syncthreads();
    }

    const int r4 = (lane >> 4) * 4, cl = lane & 15;
#pragma unroll
    for (int mi = 0; mi < 4; ++mi)
#pragma unroll
        for (int ni = 0; ni < 2; ++ni) {
            int col = n0 + wc * 32 + ni * 16 + cl;
            float bb = bias[col];
#pragma unroll
            for (int r = 0; r < 4; ++r) {
                int row = m0 + wr * 64 + mi * 16 + r4 + r;
                float v = acc0[mi][ni][r] + INV2048 * acc1[mi][ni][r] + bb;
                halfT a = (halfT)v;  float r1 = v - (float)a;
                halfT b = (halfT)(r1 * 2048.0f);
                size_t o = (size_t)row * D_ + col;
                Pa[o] = h2u(a); Pb[o] = h2u(b);
            }
        }
}

// ---------------------------------------------------------------------------
// attn_scores_h: fp16 2-plane split scores + mask + pheromone + per-chunk
// top-8. (R19-proven, unchanged.)
// ---------------------------------------------------------------------------
__global__ __launch_bounds__(512, 2)
void attn_scores_h(const ushortT* __restrict__ Qa, const ushortT* __restrict__ QB,
                   const ushortT* __restrict__ Ka, const ushortT* __restrict__ KB,
                   const float* __restrict__ pher,
                   float* __restrict__ WV, int* __restrict__ WI)
{
    __shared__ ushortT TT[16384];   // 32KB single buffer
    __shared__ float Ps[128];
    __shared__ float PV[32 * 4 * 8];
    __shared__ int   PI[32 * 4 * 8];
    float* MV = reinterpret_cast<float*>(&TT[0]);                 // [32][128]
    int*   MI = reinterpret_cast<int*>((char*)&TT[0] + 16384);    // [32][128]

    int lin = blockIdx.y * 136 + blockIdx.x;              // 0..543
    lin = (lin & 7) * 68 + (lin >> 3);                    // XCD-chunked, 544=8*68
    const int b = lin / 136;
    const int xy = lin - b * 136;
    int g = 0;
    while ((g + 1) * (g + 2) / 2 <= xy) ++g;
    const int ch = xy - g * (g + 1) / 2;
    const int n0 = g * 128;
    const int m0 = ch * 128;
    const size_t bN = (size_t)b * N_;

    const int tid = threadIdx.x;
    const int wid = tid >> 6, lane = tid & 63;
    const int wr = wid >> 2, wc = wid & 3;

    if (tid < 128) Ps[tid] = pher[bN + m0 + tid];

    const int pl = wid >> 1;
    const int hb = (wid & 1) * 64;
    const ushortT* gp = (pl == 0) ? Qa : (pl == 1) ? QB : (pl == 2) ? Ka : KB;
    const size_t rbase = bN + (pl < 2 ? n0 : m0) + hb + (lane >> 2);
    const int cg8 = ((lane & 3) ^ ((lane >> 3) & 3)) << 3;
    const size_t goff = rbase * (size_t)D_ + cg8;
    ushortT* lb0 = &TT[pl * 4096 + hb * 32];

    f32x4 acc0[4][2], acc1[4][2];
#pragma unroll
    for (int mi = 0; mi < 4; ++mi) {
        acc0[mi][0] = (f32x4){0,0,0,0}; acc0[mi][1] = (f32x4){0,0,0,0};
        acc1[mi][0] = (f32x4){0,0,0,0}; acc1[mi][1] = (f32x4){0,0,0,0};
    }

    for (int ks = 0; ks < 32; ++ks) {
        STAGE4(lb0, (size_t)ks * 32)
        __syncthreads();
        __builtin_amdgcn_s_setprio(1);
        SPLIT3H_COMPUTE(TT, wr, wc, lane, acc0, acc1)
        __builtin_amdgcn_s_setprio(0);
        __syncthreads();
    }

    // ---- fold to per-row top-8: 4 passes of 32 rows ----
    const int r4 = (lane >> 4) * 4, cl = lane & 15;
    for (int p = 0; p < 4; ++p) {
        __syncthreads();
        if (wr == (p >> 1)) {
#pragma unroll
            for (int mi2 = 0; mi2 < 2; ++mi2) {
                const int mi = (p & 1) * 2 + mi2;
#pragma unroll
                for (int ni = 0; ni < 2; ++ni) {
                    int col = wc * 32 + ni * 16 + cl;
                    int m = m0 + col;
#pragma unroll
                    for (int r = 0; r < 4; ++r) {
                        int rloc = mi2 * 16 + r4 + r;
                        int n = n0 + p * 32 + rloc;
                        bool ok = (m <= n);
                        float sc = acc0[mi][ni][r] + INV2048 * acc1[mi][ni][r];
                        MV[rloc * 128 + col] = ok ? (sc * SCALE_ + ALPHA_ * Ps[col])
                                                  : -INFINITY;
                        MI[rloc * 128 + col] = ok ? m : 0x7fffffff;
                    }
                }
            }
        }
        __syncthreads();
        if (tid < 128) {
            const int row = tid >> 2, q4 = tid & 3;
            float tv[KTOP]; int ti[KTOP];
#pragma unroll
            for (int j = 0; j < KTOP; ++j) { tv[j] = -INFINITY; ti[j] = 0x7fffffff; }
            for (int j = 0; j < 32; ++j) {
                float s2 = MV[row * 128 + q4 * 32 + j];
                if (s2 == -INFINITY) continue;
                topk_insert(tv, ti, s2, MI[row * 128 + q4 * 32 + j]);
            }
#pragma unroll
            for (int j = 0; j < KTOP; ++j) {
                PV[(row * 4 + q4) * 8 + j] = tv[j];
                PI[(row * 4 + q4) * 8 + j] = ti[j];
            }
        }
        __syncthreads();
        if (tid < 32) {
            float tv[KTOP]; int ti[KTOP];
#pragma unroll
            for (int j = 0; j < KTOP; ++j) { tv[j] = -INFINITY; ti[j] = 0x7fffffff; }
            for (int i = 0; i < 32; ++i) {
                float s2 = PV[tid * 32 + i];
                if (s2 == -INFINITY) continue;
                topk_insert(tv, ti, s2, PI[tid * 32 + i]);
            }
            int n = n0 + p * 32 + tid;
            size_t base = ((bN + n) * NCH + ch) * 8;
#pragma unroll
            for (int j = 0; j < KTOP; ++j) { WV[base + j] = tv[j]; WI[base + j] = ti[j]; }
        }
    }
}

// ---------------------------------------------------------------------------
// attn_merge: merge <=16 chunk lists -> top-8 -> softmax -> gather fp16 V ->
// CCb right half (fp16). Grid 2048 blocks, 4 rows each.
// ---------------------------------------------------------------------------
__global__ __launch_bounds__(256)
void attn_merge(const float* __restrict__ WV, const int* __restrict__ WI,
                const ushortT* __restrict__ V, ushortT* __restrict__ CCb)
{
    __shared__ float CV[4][128];
    __shared__ int   CI[4][128];
    __shared__ float Pp[4][KTOP];
    __shared__ int   Pi[4][KTOP];

    const int tid  = threadIdx.x;
    const int wv   = tid >> 6;
    const int lane = tid & 63;
    const int rid  = blockIdx.x * 4 + wv;
    const int b    = rid >> 11;
    const int n    = rid & (N_ - 1);
    const int ncand = ((n >> 7) + 1) * 8;
    const size_t cbase = (size_t)rid * (NCH * 8);

#pragma unroll
    for (int t = 0; t < 2; ++t) {
        int i = lane + t * 64;
        if (i < ncand) { CV[wv][i] = WV[cbase + i]; CI[wv][i] = WI[cbase + i]; }
        else           { CV[wv][i] = -INFINITY;     CI[wv][i] = 0x7fffffff;   }
    }
    __syncthreads();

    if (lane == 0) {
        float tv[KTOP]; int ti[KTOP];
#pragma unroll
        for (int j = 0; j < KTOP; ++j) { tv[j] = -INFINITY; ti[j] = 0x7fffffff; }
        for (int i = 0; i < 128; ++i) {
            float s = CV[wv][i];
            if (s == -INFINITY) continue;
            topk_insert(tv, ti, s, CI[wv][i]);
        }
        float mx = tv[0];
        float e[KTOP]; float sum = 0.f;
#pragma unroll
        for (int j = 0; j < KTOP; ++j) {
            e[j] = (tv[j] == -INFINITY) ? 0.f : __expf(tv[j] - mx);
            sum += e[j];
        }
        float inv = 1.f / sum;
#pragma unroll
        for (int j = 0; j < KTOP; ++j) {
            Pp[wv][j] = e[j] * inv;
            Pi[wv][j] = (tv[j] == -INFINITY) ? 0 : ti[j];
        }
    }
    __syncthreads();

    const size_t vbase = (size_t)b * N_ * D_;
#pragma unroll
    for (int it = 0; it < 2; ++it) {
        int c8 = (it * 64 + lane) * 8;
        float o[8];
#pragma unroll
        for (int u = 0; u < 8; ++u) o[u] = 0.f;
#pragma unroll
        for (int j = 0; j < KTOP; ++j) {
            float p = Pp[wv][j];
            ushort4 v0 = *reinterpret_cast<const ushort4*>(
                &V[vbase + (size_t)Pi[wv][j] * D_ + c8]);
            ushort4 v1 = *reinterpret_cast<const ushort4*>(
                &V[vbase + (size_t)Pi[wv][j] * D_ + c8 + 4]);
            o[0] = fmaf(p, uh2f(v0.x), o[0]); o[1] = fmaf(p, uh2f(v0.y), o[1]);
            o[2] = fmaf(p, uh2f(v0.z), o[2]); o[3] = fmaf(p, uh2f(v0.w), o[3]);
            o[4] = fmaf(p, uh2f(v1.x), o[4]); o[5] = fmaf(p, uh2f(v1.y), o[5]);
            o[6] = fmaf(p, uh2f(v1.z), o[6]); o[7] = fmaf(p, uh2f(v1.w), o[7]);
        }
        ushort4 ob0 = {h2u((halfT)o[0]), h2u((halfT)o[1]), h2u((halfT)o[2]), h2u((halfT)o[3])};
        ushort4 ob1 = {h2u((halfT)o[4]), h2u((halfT)o[5]), h2u((halfT)o[6]), h2u((halfT)o[7])};
        *reinterpret_cast<ushort4*>(&CCb[(size_t)rid * 2048 + 1024 + c8]) = ob0;
        *reinterpret_cast<ushort4*>(&CCb[(size_t)rid * 2048 + 1024 + c8 + 4]) = ob1;
    }
}

// ---------------------------------------------------------------------------
extern "C" void kernel_launch(void* const* d_in, const int* in_sizes, int n_in,
                              void* d_out, int out_size, void* d_ws, size_t ws_size,
                              hipStream_t stream)
{
    const float* mu   = (const float*)d_in[0];
    const float* pher = (const float*)d_in[1];
    const float* Wq   = (const float*)d_in[2];
    const float* bq   = (const float*)d_in[3];
    const float* Wk   = (const float*)d_in[4];
    const float* bk   = (const float*)d_in[5];
    const float* Wv   = (const float*)d_in[6];
    const float* bv   = (const float*)d_in[7];
    const float* Wm1  = (const float*)d_in[8];
    const float* bm1  = (const float*)d_in[9];
    const float* Wm2  = (const float*)d_in[10];
    const float* bm2  = (const float*)d_in[11];
    const float* Wo   = (const float*)d_in[12];
    const float* bo   = (const float*)d_in[13];
    float* out = (float*)d_out;
    float* ws  = (float*)d_ws;

    const size_t SZ  = (size_t)B_ * N_ * D_;    // 8388608 floats
    const size_t MEG = 1024 * 1024;             // floats
    const int M = B_ * N_;                      // 8192

    // ---- workspace map (float units). Vb16 disjoint from Sb. ----
    ushortT* CCb  = (ushortT*)ws;                         // [8192][2048] fp16 [0,SZ)
    float*   PF   = ws + SZ;                              // [SZ,3SZ) f32 pre-act
    ushortT* Qa   = (ushortT*)(ws + SZ);                  // overlay PF (after silu)
    ushortT* QB   = Qa + SZ;
    ushortT* Ka   = (ushortT*)(ws + 2 * SZ);
    ushortT* KB   = Ka + SZ;
    ushortT* mu_a = (ushortT*)(ws + 3 * SZ);              // [3SZ,3.5SZ)
    ushortT* mu_B = mu_a + SZ;                            // [3.5SZ,4SZ)
    ushortT* Sb   = (ushortT*)(ws + 4 * SZ);              // [4SZ,4SZ+4MEG) fp16 S
    float*   WVb  = (float*)(ws + 4 * SZ);                // overlay Sb (after local gemm)
    int*     WIb  = (int*)(WVb + MEG);
    ushortT* Vb16 = (ushortT*)(ws + 4 * SZ + 4 * MEG);    // disjoint from Sb
    ushortT* U    = (ushortT*)(ws + 4 * SZ + 8 * MEG);    // weights, 10M ushorts
    ushortT* WtF  = U;                   // [2048][1024] fused Wm1^T = 2M ush
    ushortT* Wt_m2 = U + 2 * MEG;        // [1024][1024] = 1M ush
    ushortT* Wt_v  = U + 3 * MEG;        // 1M ush
    ushortT* WqT_a = U + 4 * MEG;        ushortT* WqT_B = U + 5 * MEG;
    ushortT* WkT_a = U + 6 * MEG;        ushortT* WkT_B = U + 7 * MEG;
    ushortT* Wt_o  = U + 8 * MEG;        // [1024][2048] = 2M ush

    dim3 blk256(256), blk512(512);
    dim3 gD(8, 64);

    // 1. ALL prep: mu split + 7 weight transposes (one launch)
    hipLaunchKernelGGL(prep_all, dim3(16384), blk256, 0, stream,
                       mu, Wm1, Wm2, Wv, Wo, Wq, Wk,
                       mu_a, mu_B, WtF, Wt_m2, Wt_v, Wt_o,
                       WqT_a, WqT_B, WkT_a, WkT_B);
    // 2. PF pre-act gemm + V gemm (merged, 1536 blocks)
    hipLaunchKernelGGL(gemm_pf_v, dim3(1536), blk256, 0, stream,
                       mu_a, WtF, Wt_v, bv, PF, Vb16);
    // 3. silu-mean (consumes PF) -> Sb. PF dead after.
    hipLaunchKernelGGL(silu_mean, dim3(SZ / 4 / 256), blk256, 0, stream, PF, bm1, Sb);
    // 4. MERGED: Q/K projections (overlay dead PF) + local gemm (Sb -> CCb)
    hipLaunchKernelGGL(mid_all, dim3(1536), blk512, 0, stream,
                       mu_a, mu_B, WqT_a, WqT_B, WkT_a, WkT_B,
                       bq, bk, Qa, QB, Ka, KB,
                       Sb, Wt_m2, bm2, CCb);
    // 5. scores + per-chunk top-8 (WVb/WIb overlay dead Sb)
    hipLaunchKernelGGL(attn_scores_h, dim3(136, B_), blk512, 0, stream,
                       Qa, QB, Ka, KB, pher, WVb, WIb);
    // 6. merge + softmax + V gather -> CCb right half
    hipLaunchKernelGGL(attn_merge, dim3(M / 4), blk256, 0, stream, WVb, WIb, Vb16, CCb);
    // 7. out = CCb @ Wo + bo (fp16 MFMA, K=2048, f32 out)
    hipLaunchKernelGGL((mfma_gemm_h<0>), gD, blk256, 0, stream,
                       CCb, 2 * D_, Wt_o, 2048, bo, (void*)out, D_, 2 * D_);

    (void)in_sizes; (void)n_in; (void)out_size; (void)ws_size;
}